// Round 5
// baseline (212.278 us; speedup 1.0000x reference)
//
#include <hip/hip_runtime.h>

#define ROW_LEN 8192
#define TOPK 8
#define THREADS 256
#define NWAVES 4      // one wave per row, 4 rows per block, zero block barriers
#define WCAP 128      // per-wave candidate cap; E[n]≈20 (T≈2.8σ), P(n>128) ~ 1e-30

__global__ __launch_bounds__(THREADS) void topk_rows_kernel(
        const float* __restrict__ x,
        float* __restrict__ out_vals,     // [n_rows, 8] float
        float* __restrict__ out_idx,      // [n_rows, 8] indices stored as float
        int n_rows) {
    const int tid  = threadIdx.x;
    const int lane = tid & 63;
    const int wave = tid >> 6;
    const int row  = blockIdx.x * NWAVES + wave;
    if (row >= n_rows) return;

    const float4* rowp = (const float4*)(x + (size_t)row * ROW_LEN);

    __shared__ float cv[NWAVES][WCAP];
    __shared__ int   ci[NWAVES][WCAP];
    __shared__ int   wcnt[NWAVES];
    if (lane == 0) wcnt[wave] = 0;   // own wave's segment; intra-wave program order

    // ---- phase 1: streaming max over 128 elems (32 coalesced float4 loads;
    // no values kept live -> deep load pipelining, low VGPR) ----
    float mx = -INFINITY;
#pragma unroll
    for (int k = 0; k < 32; k++) {
        float4 f = rowp[k * 64 + lane];
        mx = fmaxf(mx, fmaxf(fmaxf(f.x, f.y), fmaxf(f.z, f.w)));
    }

    // ---- conservative threshold in 6 shfls:
    // T = min over the 8 lane-groups (8 lanes x 128 elems = 1024 elems each)
    // of the group max. The 8 group maxima are 8 distinct row positions all
    // >= T, so the row's 8th-largest >= T -> every top-8 element passes. ----
    float m = mx;
#pragma unroll
    for (int d = 1; d <= 4; d <<= 1) m = fmaxf(m, __shfl_xor(m, d, 64));
#pragma unroll
    for (int d = 8; d <= 32; d <<= 1) m = fminf(m, __shfl_xor(m, d, 64));
    const float T = m;   // identical on all 64 lanes

    // ---- phase 2: gated rescan (only ~15-20 lanes/wave have mx >= T; their
    // re-loads hit L1/L2 since this CU just streamed the row). ~20 DS atomics
    // per wave into the wave's own segment — no cross-wave contention. ----
    if (mx >= T) {
#pragma unroll
        for (int k = 0; k < 32; k++) {
            float4 f = rowp[k * 64 + lane];
            float vv[4] = {f.x, f.y, f.z, f.w};
#pragma unroll
            for (int j = 0; j < 4; j++) {
                if (vv[j] >= T) {
                    int p = atomicAdd(&wcnt[wave], 1);
                    if (p < WCAP) {          // memory-safety clamp only
                        cv[wave][p] = vv[j];
                        ci[wave][p] = 4 * (k * 64 + lane) + j;
                    }
                }
            }
        }
    }
    // lanes reconverge here; wave's own LDS writes are ordered by lgkmcnt.

    // ---- per-wave rank-select tail (~20 candidates): rank by
    // (value desc, index asc) — exact lax.top_k order, ranks unique via
    // index tiebreak -> exactly 8 race-free writers. ----
    int n = wcnt[wave];
    if (n > WCAP) n = WCAP;
    for (int c = lane; c < n; c += 64) {
        const float myv = cv[wave][c];
        const int   myi = ci[wave][c];
        int rank = 0;
        for (int j = 0; j < n; j++) {
            const float ov = cv[wave][j];
            const int   oi = ci[wave][j];
            rank += (ov > myv) || (ov == myv && oi < myi);
        }
        if (rank < TOPK) {
            out_vals[(size_t)row * TOPK + rank] = myv;
            out_idx[(size_t)row * TOPK + rank]  = (float)myi;
        }
    }
}

extern "C" void kernel_launch(void* const* d_in, const int* in_sizes, int n_in,
                              void* d_out, int out_size, void* d_ws, size_t ws_size,
                              hipStream_t stream) {
    const float* x = (const float*)d_in[0];
    float* out = (float*)d_out;
    const int n_rows = in_sizes[0] / ROW_LEN;               // 4096
    float* out_vals = out;                                   // values, flat [n_rows*8]
    float* out_idx  = out + (size_t)n_rows * TOPK;           // indices (as float)

    const int grid = (n_rows + NWAVES - 1) / NWAVES;         // 1024 blocks, 4 waves each
    topk_rows_kernel<<<grid, THREADS, 0, stream>>>(x, out_vals, out_idx, n_rows);
}

// Round 6
// 188.245 us; speedup vs baseline: 1.1277x; 1.1277x over previous
//
#include <hip/hip_runtime.h>

#define ROW_LEN 8192
#define TOPK 8
#define THREADS 256
#define CAND_CAP 128   // E[#cands]≈20 with block-level T; P(>128) astronomically small

__global__ __launch_bounds__(THREADS) void topk_rows_kernel(
        const float* __restrict__ x,
        float* __restrict__ out_vals,     // [n_rows, 8] float
        float* __restrict__ out_idx,      // [n_rows, 8] indices stored as float
        int n_rows) {
    const int row  = blockIdx.x;
    const int tid  = threadIdx.x;
    const int lane = tid & 63;
    const int wave = tid >> 6;
    if (row >= n_rows) return;

    const float4* rowp = (const float4*)(x + (size_t)row * ROW_LEN);

    __shared__ float gmax[8];          // 8 half-wave maxima (1024 elems each)
    __shared__ int   cnt;
    __shared__ float cand_v[CAND_CAP];
    __shared__ int   cand_i[CAND_CAP];
    if (tid == 0) cnt = 0;

    // ---- phase 1: pure streaming max (8 coalesced float4 loads, nothing
    // else in the loop -> deep pipelining, low VGPR, high occupancy) ----
    float mx = -INFINITY;
#pragma unroll
    for (int k = 0; k < 8; k++) {
        float4 f = rowp[k * THREADS + tid];
        mx = fmaxf(mx, fmaxf(fmaxf(f.x, f.y), fmaxf(f.z, f.w)));
    }

    // ---- block-level conservative threshold:
    // half-wave (32-lane) max = max over 1024 distinct row elements.
    // T = min of the block's 8 half-wave maxima -> 8 distinct positions >= T
    // -> row's 8th-largest >= T -> no top-8 element is filtered out. ----
    float hm = mx;
#pragma unroll
    for (int d = 1; d <= 16; d <<= 1) hm = fmaxf(hm, __shfl_xor(hm, d, 64));
    if ((lane & 31) == 0) gmax[wave * 2 + (lane >> 5)] = hm;
    __syncthreads();                   // gmax ready; cnt initialized

    float T = gmax[0];
#pragma unroll
    for (int g = 1; g < 8; g++) T = fminf(T, gmax[g]);

    // ---- phase 2: gated rescan. Only ~20 threads/block pass (mx >= T);
    // their reloads hit L1/L2 (row just streamed by this CU). ~20 LDS
    // atomics per block. ----
    if (mx >= T) {
#pragma unroll
        for (int k = 0; k < 8; k++) {
            float4 f = rowp[k * THREADS + tid];
            float vv[4] = {f.x, f.y, f.z, f.w};
#pragma unroll
            for (int j = 0; j < 4; j++) {
                if (vv[j] >= T) {
                    int p = atomicAdd(&cnt, 1);
                    if (p < CAND_CAP) {      // memory-safety clamp only
                        cand_v[p] = vv[j];
                        cand_i[p] = 4 * (k * THREADS + tid) + j;
                    }
                }
            }
        }
    }
    __syncthreads();

    // ---- wave-0 rank-select over n≈20: rank by (value desc, index asc) —
    // exact lax.top_k tie order; ranks unique via index tiebreak ->
    // exactly 8 race-free writers. Other waves retire meanwhile. ----
    if (tid < 64) {
        int n = cnt;
        if (n > CAND_CAP) n = CAND_CAP;
        for (int c = tid; c < n; c += 64) {
            const float myv = cand_v[c];
            const int   myi = cand_i[c];
            int rank = 0;
            for (int j = 0; j < n; j++) {
                const float ov = cand_v[j];
                const int   oi = cand_i[j];
                rank += (ov > myv) || (ov == myv && oi < myi);
            }
            if (rank < TOPK) {
                out_vals[(size_t)row * TOPK + rank] = myv;
                out_idx[(size_t)row * TOPK + rank]  = (float)myi;
            }
        }
    }
}

extern "C" void kernel_launch(void* const* d_in, const int* in_sizes, int n_in,
                              void* d_out, int out_size, void* d_ws, size_t ws_size,
                              hipStream_t stream) {
    const float* x = (const float*)d_in[0];
    float* out = (float*)d_out;
    const int n_rows = in_sizes[0] / ROW_LEN;          // 4096
    float* out_vals = out;                              // values, flat [n_rows*8]
    float* out_idx  = out + (size_t)n_rows * TOPK;      // indices (as float)

    topk_rows_kernel<<<n_rows, THREADS, 0, stream>>>(x, out_vals, out_idx, n_rows);
}